// Round 1
// baseline (126.257 us; speedup 1.0000x reference)
//
#include <hip/hip_runtime.h>

typedef unsigned int   u32;
typedef unsigned short u16;

using f32x4  = __attribute__((ext_vector_type(4))) float;
using bf16x8 = __attribute__((ext_vector_type(8))) short;

#define DEV static __device__ __forceinline__

DEV u16 f2bf(float f){
  union { float f; u32 u; } v; v.f = f;
  u32 r = v.u + 0x7FFFu + ((v.u >> 16) & 1u);   // RNE
  return (u16)(r >> 16);
}
DEV short f2bf_s(float f){ return (short)f2bf(f); }
DEV float bf2f(u16 b){
  union { u32 u; float f; } v; v.u = ((u32)b) << 16;
  return v.f;
}

// ---------------- transpose (R,32) f32 -> (32,R) {f32|bf16} ----------------
template<bool BF16OUT>
__global__ __launch_bounds__(256)
void transpose32(const float* __restrict__ in, void* __restrict__ outv, int R){
  __shared__ float tile[32][33];
  const int tid = threadIdx.x;
  const int r0  = blockIdx.x << 5;
  const int c   = tid & 31;
  const int rp  = tid >> 5;
#pragma unroll
  for (int p = 0; p < 4; ++p){
    const int r = (p << 3) + rp;
    tile[r][c] = in[(size_t)(r0 + r) * 32 + c];
  }
  __syncthreads();
#pragma unroll
  for (int p = 0; p < 4; ++p){
    const int dd = (p << 3) + rp;
    const float v = tile[c][dd];
    if constexpr (BF16OUT) ((u16*)outv)[(size_t)dd * R + r0 + c] = f2bf(v);
    else                   ((float*)outv)[(size_t)dd * R + r0 + c] = v;
  }
}

// ---------------- CIN step as MFMA GEMM, one d per block ----------------
// y[d][b][o] = relu(bias[o] + sum_k xk[b, k/40] * x0[b, k%40] * W[d][o][k])
// H=40: xk = x0 (f32 tile).  H=64: xk = x1 (bf16, staged).
template<int H>
__global__ __launch_bounds__(256, 2)
void cin_gemm(const float* __restrict__ xt,     // [32][2048][40] f32
              const u16*   __restrict__ xkt,    // [32][2048][64] bf16 (H==64)
              const u16*   __restrict__ Wp,     // [32][64][K]    bf16
              const float* __restrict__ bias,   // [64]
              u16*         __restrict__ yt)     // [32][2048][64] bf16
{
  constexpr int K = H * 40;
  constexpr int NSTEP = K / 64;
  const int d   = blockIdx.x & 31;
  const int bt  = blockIdx.x >> 5;
  const int b0  = bt << 7;            // *128
  const int tid = threadIdx.x;
  const int w   = tid >> 6;
  const int l   = tid & 63;
  const int lg  = l >> 4;             // lane group 0..3
  const int ll  = l & 15;

  __shared__ float x0s[128][43];                         // pad -> conflict-lite
  __shared__ u16   xks[(H==64)?128:1][(H==64)?66:2];
  __shared__ u16   Bs[64][72];                           // [o][kk], pad 64->72

  { // stage x0 tile (contiguous global chunk)
    const float* src = xt + (size_t)d * (2048*40) + (size_t)b0 * 40;
    for (int idx = tid; idx < 128*40; idx += 256){
      const int r = idx / 40;
      x0s[r][idx - r*40] = src[idx];
    }
  }
  if constexpr (H == 64){ // stage x1 tile as u32 pairs
    const u32* src = (const u32*)(xkt + (size_t)d * (2048*64) + (size_t)b0 * 64);
    for (int idx = tid; idx < 128*32; idx += 256){
      const int r = idx >> 5, c2 = (idx & 31) << 1;
      *(u32*)&xks[r][c2] = src[idx];
    }
  }
  __syncthreads();

  const f32x4 fz = {0.f, 0.f, 0.f, 0.f};
  f32x4 acc[2][4];
#pragma unroll
  for (int m = 0; m < 2; ++m)
#pragma unroll
    for (int n = 0; n < 4; ++n) acc[m][n] = fz;

  const int rowA0 = (w << 5) + ll;    // wave owns rows [w*32, w*32+32)
  const int rowA1 = rowA0 + 16;

  // incremental k -> (h,f): runs start at lg*8 and advance +32 per ksub
  int h_run = 0, f_run = lg << 3;

  const u16* wsrc = Wp + (size_t)d * (64*K);
  const int wo = tid >> 2, wc = tid & 3;

  for (int ks = 0; ks < NSTEP; ++ks){
    const int k0 = ks << 6;
    // W tile -> regs (overlaps previous compute), then regs -> LDS
    const uint4* gw = (const uint4*)(wsrc + (size_t)wo * K + k0 + (wc << 4));
    const uint4 wreg0 = gw[0];
    const uint4 wreg1 = gw[1];
    __syncthreads();                       // prior readers of Bs done
    {
      uint4* bdst = (uint4*)&Bs[wo][wc << 4];
      bdst[0] = wreg0;
      bdst[1] = wreg1;
    }
    __syncthreads();                       // Bs ready

#pragma unroll
    for (int ksub = 0; ksub < 2; ++ksub){
      const int hc = (h_run + 1 < H) ? h_run + 1 : h_run;   // clamped h+1
      float xh00, xh01, xh10, xh11;
      if constexpr (H == 64){
        xh00 = bf2f(xks[rowA0][h_run]); xh01 = bf2f(xks[rowA0][hc]);
        xh10 = bf2f(xks[rowA1][h_run]); xh11 = bf2f(xks[rowA1][hc]);
      } else {
        xh00 = x0s[rowA0][h_run]; xh01 = x0s[rowA0][hc];
        xh10 = x0s[rowA1][h_run]; xh11 = x0s[rowA1][hc];
      }
      bf16x8 a0, a1;
#pragma unroll
      for (int e = 0; e < 8; ++e){
        const int  fe  = f_run + e;
        const bool wr  = fe >= 40;
        const int  fe2 = wr ? fe - 40 : fe;
        const float xa = x0s[rowA0][fe2];
        const float xb = x0s[rowA1][fe2];
        a0[e] = f2bf_s((wr ? xh01 : xh00) * xa);
        a1[e] = f2bf_s((wr ? xh11 : xh10) * xb);
      }
      const int kb = (ksub << 5) + (lg << 3);
#pragma unroll
      for (int n = 0; n < 4; ++n){
        const bf16x8 bf = *(const bf16x8*)&Bs[(n << 4) + ll][kb];
        acc[0][n] = __builtin_amdgcn_mfma_f32_16x16x32_bf16(a0, bf, acc[0][n], 0, 0, 0);
        acc[1][n] = __builtin_amdgcn_mfma_f32_16x16x32_bf16(a1, bf, acc[1][n], 0, 0, 0);
      }
      f_run += 32;
      if (f_run >= 40){ f_run -= 40; ++h_run; }
    }
  }

  float bv[4];
#pragma unroll
  for (int n = 0; n < 4; ++n) bv[n] = bias[(n << 4) + ll];

  u16* ydst = yt + (size_t)d * (2048*64);
#pragma unroll
  for (int m = 0; m < 2; ++m)
#pragma unroll
    for (int n = 0; n < 4; ++n)
#pragma unroll
      for (int r = 0; r < 4; ++r){
        const int b = b0 + (w << 5) + (m << 4) + (lg << 2) + r;
        const int o = (n << 4) + ll;
        float v = acc[m][n][r] + bv[n];
        v = v > 0.f ? v : 0.f;
        ydst[(size_t)b * 64 + o] = f2bf(v);
      }
}

// ---------------- final: out[b, :] = sum_d concat(x, x1, x2) ----------------
__global__ __launch_bounds__(192)
void finalize(const float* __restrict__ x, const u16* __restrict__ x1t,
              const u16* __restrict__ y2t, float* __restrict__ out){
  const int b = blockIdx.x;
  const int t = threadIdx.x;
  if (t < 40){
    const float4* p = (const float4*)(x + ((size_t)b * 40 + t) * 32);
    float s = 0.f;
#pragma unroll
    for (int q = 0; q < 8; ++q){
      const float4 v = p[q];
      s += v.x + v.y + v.z + v.w;
    }
    out[(size_t)b * 168 + t] = s;
  } else if (t < 104){
    const int o = t - 40;
    float s = 0.f;
#pragma unroll
    for (int d = 0; d < 32; ++d) s += bf2f(x1t[(size_t)d * (2048*64) + (size_t)b * 64 + o]);
    out[(size_t)b * 168 + t] = s;
  } else if (t < 168){
    const int o = t - 104;
    float s = 0.f;
#pragma unroll
    for (int d = 0; d < 32; ++d) s += bf2f(y2t[(size_t)d * (2048*64) + (size_t)b * 64 + o]);
    out[(size_t)b * 168 + t] = s;
  }
}

extern "C" void kernel_launch(void* const* d_in, const int* in_sizes, int n_in,
                              void* d_out, int out_size, void* d_ws, size_t ws_size,
                              hipStream_t stream){
  const float* x   = (const float*)d_in[0];
  const float* W0  = (const float*)d_in[1];
  const float* b0v = (const float*)d_in[2];
  const float* W1  = (const float*)d_in[3];
  const float* b1v = (const float*)d_in[4];
  float* out = (float*)d_out;

  char* ws = (char*)d_ws;
  float* xt  = (float*)(ws + 0);          // 32*2048*40*4  = 10,485,760
  u16*   W0p = (u16*)(ws + 10485760);     // 32*64*1600*2  =  6,553,600
  u16*   W1p = (u16*)(ws + 17039360);     // 32*64*2560*2  = 10,485,760
  u16*   x1t = (u16*)(ws + 27525120);     // 32*2048*64*2  =  8,388,608
  u16*   y2t = (u16*)(ws + 35913728);     // 32*2048*64*2  =  8,388,608
  // total ws use: 44,302,336 bytes

  transpose32<false><<<2560, 256, 0, stream>>>(x,  xt,  81920);    // (B*F,32)->xt
  transpose32<true ><<<3200, 256, 0, stream>>>(W0, W0p, 102400);   // (O*K1,32)->W0p
  transpose32<true ><<<5120, 256, 0, stream>>>(W1, W1p, 163840);   // (O*K2,32)->W1p

  cin_gemm<40><<<512, 256, 0, stream>>>(xt, nullptr, W0p, b0v, x1t);
  cin_gemm<64><<<512, 256, 0, stream>>>(xt, x1t,     W1p, b1v, y2t);

  finalize<<<2048, 192, 0, stream>>>(x, x1t, y2t, out);
}

// Round 2
// 118.733 us; speedup vs baseline: 1.0634x; 1.0634x over previous
//
#include <hip/hip_runtime.h>

typedef unsigned int   u32;
typedef unsigned short u16;
typedef _Float16       f16;

using f16x8 = __attribute__((ext_vector_type(8))) _Float16;
using f32x4 = __attribute__((ext_vector_type(4))) float;

// ---------------- transpose (R,32) f32 -> (32,R) f16 ----------------
__global__ __launch_bounds__(256)
void transpose32(const float* __restrict__ in, f16* __restrict__ out, int R){
  __shared__ float tile[32][33];
  const int tid = threadIdx.x;
  const int r0  = blockIdx.x << 5;
  const int c   = tid & 31;
  const int rp  = tid >> 5;
#pragma unroll
  for (int p = 0; p < 4; ++p){
    const int r = (p << 3) + rp;
    tile[r][c] = in[(size_t)(r0 + r) * 32 + c];
  }
  __syncthreads();
#pragma unroll
  for (int p = 0; p < 4; ++p){
    const int dd = (p << 3) + rp;
    out[(size_t)dd * R + r0 + c] = (f16)tile[c][dd];
  }
}

// ---------------- CIN step as MFMA GEMM, one d per block ----------------
// y[d][b][o] = relu(bias[o] + sum_k xk[b,k/40] * x0[b,k%40] * W[d][o][k])
// A-fragment built in-register via lg-rotated 8-element f-slots (40 = 5*8,
// K-runs of 8 never straddle an 8-aligned f-block).
template<int H>
__global__ __launch_bounds__(256, 2)
void cin_gemm(const f16* __restrict__ xt,     // [32][2048][40] f16
              const f16* __restrict__ xkt,    // [32][2048][64] f16 (H==64)
              const f16* __restrict__ Wp,     // [32][64][K]    f16
              const float* __restrict__ bias, // [64]
              f16*       __restrict__ yt)     // [32][2048][64] f16
{
  constexpr int K     = H * 40;
  constexpr int BK    = 160;            // 5 ksubs of 32
  constexpr int NSTEP = K / BK;         // 10 (H=40) or 16 (H=64)
  const int d   = blockIdx.x & 31;
  const int bt  = blockIdx.x >> 5;
  const int b0  = bt << 7;              // *128
  const int tid = threadIdx.x;
  const int w   = tid >> 6;
  const int l   = tid & 63;
  const int lg  = l >> 4;               // lane group 0..3 (k-subrange)
  const int ll  = l & 15;

  __shared__ f16 x0s[128][48];                          // row stride 96B
  __shared__ f16 xks[(H==64)?128:1][(H==64)?72:2];      // row stride 144B
  __shared__ f16 Bs[64][168];                           // row stride 336B

  const f16* wsrc = Wp + (size_t)d * (64 * K);
  const int  wrow = tid >> 2;           // 0..63  (o row)
  const int  wq   = tid & 3;            // quarter of a 320B row
  const uint4* gwbase = (const uint4*)wsrc + (size_t)wrow * (K / 8) + wq * 5;

  uint4 wreg[5];
#pragma unroll
  for (int i = 0; i < 5; ++i) wreg[i] = gwbase[i];      // prefetch ks=0

  { // stage x0 tile: 128 rows * 80B, uint4 granules
    const uint4* src = (const uint4*)(xt + (size_t)d * (2048*40) + (size_t)b0 * 40);
#pragma unroll
    for (int i = 0; i < 3; ++i){
      const int idx = tid + (i << 8);
      if (idx < 640){
        const int r = idx / 5, cc = idx - r * 5;
        *(uint4*)((char*)&x0s[r][0] + cc * 16) = src[idx];
      }
    }
  }
  if constexpr (H == 64){ // stage x1 tile: 128 rows * 128B
    const uint4* src = (const uint4*)(xkt + (size_t)d * (2048*64) + (size_t)b0 * 64);
#pragma unroll
    for (int i = 0; i < 4; ++i){
      const int idx = tid + (i << 8);
      const int r = idx >> 3, cc = idx & 7;
      *(uint4*)((char*)&xks[r][0] + cc * 16) = src[idx];
    }
  }
  __syncthreads();

  const int rowA0 = (w << 5) + ll;      // wave owns rows [w*32, w*32+32)
  const int rowA1 = rowA0 + 16;

  // lg-rotated slot preload: slot[t] holds f-block (4t+lg)%5 of the x-row
  f16x8 sl0[5], sl1[5];
  int   hd[5];
#pragma unroll
  for (int t = 0; t < 5; ++t){
    const int v = 4 * t + lg;
    const int j = v % 5;
    hd[t] = v / 5;
    sl0[t] = *(const f16x8*)((const char*)&x0s[rowA0][0] + j * 16);
    sl1[t] = *(const f16x8*)((const char*)&x0s[rowA1][0] + j * 16);
  }

  { // write prefetched W tile (ks=0)
    uint4* bdst = (uint4*)((char*)&Bs[wrow][0] + wq * 80);
#pragma unroll
    for (int i = 0; i < 5; ++i) bdst[i] = wreg[i];
  }
  __syncthreads();

  const f32x4 fz = {0.f, 0.f, 0.f, 0.f};
  f32x4 acc[2][4];
#pragma unroll
  for (int m = 0; m < 2; ++m)
#pragma unroll
    for (int n = 0; n < 4; ++n) acc[m][n] = fz;

  const f16* bsbase = &Bs[ll][lg << 3];

  for (int ks = 0; ks < NSTEP; ++ks){
    if (ks + 1 < NSTEP){                // prefetch next W tile into regs
      const uint4* gw = gwbase + (ks + 1) * 20;
#pragma unroll
      for (int i = 0; i < 5; ++i) wreg[i] = gw[i];
    }
    const int hb = ks << 2;
#pragma unroll
    for (int s = 0; s < 5; ++s){
      const int h = hb + hd[s];
      f16 xh0, xh1;
      if constexpr (H == 64){ xh0 = xks[rowA0][h]; xh1 = xks[rowA1][h]; }
      else                  { xh0 = x0s[rowA0][h]; xh1 = x0s[rowA1][h]; }
      const f16x8 a0 = sl0[s] * xh0;    // 4x v_pk_mul_f16
      const f16x8 a1 = sl1[s] * xh1;
#pragma unroll
      for (int n = 0; n < 4; ++n){
        const f16x8 bf = *(const f16x8*)(bsbase + n * (16 * 168) + (s << 5));
        acc[0][n] = __builtin_amdgcn_mfma_f32_16x16x32_f16(a0, bf, acc[0][n], 0, 0, 0);
        acc[1][n] = __builtin_amdgcn_mfma_f32_16x16x32_f16(a1, bf, acc[1][n], 0, 0, 0);
      }
    }
    __syncthreads();                    // all reads of Bs done
    if (ks + 1 < NSTEP){
      uint4* bdst = (uint4*)((char*)&Bs[wrow][0] + wq * 80);
#pragma unroll
      for (int i = 0; i < 5; ++i) bdst[i] = wreg[i];
      __syncthreads();                  // Bs ready for next step
    }
  }

  float bv[4];
#pragma unroll
  for (int n = 0; n < 4; ++n) bv[n] = bias[(n << 4) + ll];

  f16* ydst = yt + (size_t)d * (2048*64);
#pragma unroll
  for (int m = 0; m < 2; ++m)
#pragma unroll
    for (int n = 0; n < 4; ++n)
#pragma unroll
      for (int r = 0; r < 4; ++r){
        const int b = b0 + (w << 5) + (m << 4) + (lg << 2) + r;
        const int o = (n << 4) + ll;
        float v = acc[m][n][r] + bv[n];
        v = v > 0.f ? v : 0.f;
        ydst[(size_t)b * 64 + o] = (f16)v;
      }
}

// ---------------- final: out[b, :] = sum_d concat(x, x1, x2) ----------------
__global__ __launch_bounds__(192)
void finalize(const float* __restrict__ x, const f16* __restrict__ x1t,
              const f16* __restrict__ y2t, float* __restrict__ out){
  const int b = blockIdx.x;
  const int t = threadIdx.x;
  if (t < 40){
    const float4* p = (const float4*)(x + ((size_t)b * 40 + t) * 32);
    float s = 0.f;
#pragma unroll
    for (int q = 0; q < 8; ++q){
      const float4 v = p[q];
      s += v.x + v.y + v.z + v.w;
    }
    out[(size_t)b * 168 + t] = s;
  } else if (t < 104){
    const int o = t - 40;
    float s = 0.f;
#pragma unroll
    for (int d = 0; d < 32; ++d) s += (float)x1t[(size_t)d * (2048*64) + (size_t)b * 64 + o];
    out[(size_t)b * 168 + t] = s;
  } else if (t < 168){
    const int o = t - 104;
    float s = 0.f;
#pragma unroll
    for (int d = 0; d < 32; ++d) s += (float)y2t[(size_t)d * (2048*64) + (size_t)b * 64 + o];
    out[(size_t)b * 168 + t] = s;
  }
}

extern "C" void kernel_launch(void* const* d_in, const int* in_sizes, int n_in,
                              void* d_out, int out_size, void* d_ws, size_t ws_size,
                              hipStream_t stream){
  const float* x   = (const float*)d_in[0];
  const float* W0  = (const float*)d_in[1];
  const float* b0v = (const float*)d_in[2];
  const float* W1  = (const float*)d_in[3];
  const float* b1v = (const float*)d_in[4];
  float* out = (float*)d_out;

  char* ws = (char*)d_ws;
  f16* xt  = (f16*)(ws + 0);            // 32*2048*40*2  =  5,242,880
  f16* W0p = (f16*)(ws + 5242880);      // 32*64*1600*2  =  6,553,600
  f16* W1p = (f16*)(ws + 11796480);     // 32*64*2560*2  = 10,485,760
  f16* x1t = (f16*)(ws + 22282240);     // 32*2048*64*2  =  8,388,608
  f16* y2t = (f16*)(ws + 30670848);     // 32*2048*64*2  =  8,388,608
  // total ws use: 39,059,456 bytes

  transpose32<<<2560, 256, 0, stream>>>(x,  xt,  81920);
  transpose32<<<3200, 256, 0, stream>>>(W0, W0p, 102400);
  transpose32<<<5120, 256, 0, stream>>>(W1, W1p, 163840);

  cin_gemm<40><<<512, 256, 0, stream>>>(xt, nullptr, W0p, b0v, x1t);
  cin_gemm<64><<<512, 256, 0, stream>>>(xt, x1t,     W1p, b1v, y2t);

  finalize<<<2048, 192, 0, stream>>>(x, x1t, y2t, out);
}

// Round 3
// 91.518 us; speedup vs baseline: 1.3796x; 1.2974x over previous
//
#include <hip/hip_runtime.h>

typedef unsigned int   u32;
typedef unsigned short u16;
typedef _Float16       f16;

using f16x8 = __attribute__((ext_vector_type(8))) _Float16;
using f16x4 = __attribute__((ext_vector_type(4))) _Float16;
using f32x4 = __attribute__((ext_vector_type(4))) float;

// ---------------- transpose (R,32) f32 -> (32,R) f16 ----------------
__global__ __launch_bounds__(256)
void transpose32(const float* __restrict__ in, f16* __restrict__ out, int R){
  __shared__ float tile[32][33];
  const int tid = threadIdx.x;
  const int r0  = blockIdx.x << 5;
  const int c   = tid & 31;
  const int rp  = tid >> 5;
#pragma unroll
  for (int p = 0; p < 4; ++p){
    const int r = (p << 3) + rp;
    tile[r][c] = in[(size_t)(r0 + r) * 32 + c];
  }
  __syncthreads();
#pragma unroll
  for (int p = 0; p < 4; ++p){
    const int dd = (p << 3) + rp;
    out[(size_t)dd * R + r0 + c] = (f16)tile[c][dd];
  }
}

// ------- W (64,K,32) f32 -> k-panel Wp [32][K/8][64][8] f16 -------
__global__ __launch_bounds__(256)
void wprep(const float* __restrict__ in, f16* __restrict__ out, int K){
  __shared__ u16 t[32 * 530];           // d-stride 530 u16 (conflict-free)
  const int kb  = blockIdx.x;           // 0..K/8-1
  const int tid = threadIdx.x;
  const int kbase = kb << 3;
#pragma unroll 4
  for (int i = 0; i < 64; ++i){
    const int idx = tid + (i << 8);
    const int o   = idx >> 8;
    const int rem = idx & 255;
    const int e   = rem >> 5;
    const int dd  = rem & 31;
    const float v = in[(size_t)o * (K * 32) + (size_t)(kbase + e) * 32 + dd];
    union { f16 h; u16 u; } cv; cv.h = (f16)v;
    t[dd * 530 + o * 8 + e] = cv.u;
  }
  __syncthreads();
  const u32* t32 = (const u32*)t;
  u32* o32 = (u32*)out;
  const int obase = kb << 8;            // kb*512 u16 = kb*256 u32
#pragma unroll 4
  for (int i = 0; i < 32; ++i){
    const int idx = tid + (i << 8);
    const int dd  = idx >> 8;
    const int rem = idx & 255;
    o32[(size_t)dd * (K * 32) + obase + rem] = t32[dd * 265 + rem];
  }
}

// ---------------- CIN step: barrier-free MFMA GEMM ----------------
// y[d][b][o] = relu(bias[o] + sum_k xk[b,k/40] * x0[b,k%40] * W[d][o][k])
// B-frags read straight from global (k-panel layout, L2-resident).
// Wave: 64 rows (4 strips of 16) x 32 o-cols.  Block: 128 x 64, 4 waves.
template<int H>
__global__ __launch_bounds__(256, 2)
void cin_gemm(const f16* __restrict__ xt,     // [32][2048*40] f16
              const f16* __restrict__ xkt,    // [32][2048*64] f16 (H==64)
              const f16* __restrict__ Wp,     // [32][K/8][64][8] f16
              const float* __restrict__ bias, // [64]
              f16*       __restrict__ yt)     // [32][2048][64] f16
{
  constexpr int K     = H * 40;
  constexpr int NSTEP = K / 160;        // 10 (H=40) or 16 (H=64)
  const int bid = blockIdx.x;
  const int d   = ((bid & 7) << 2) | (bid >> 7);   // XCD-local d groups
  const int bt  = (bid >> 3) & 15;
  const int b0  = bt << 7;
  const int tid = threadIdx.x;
  const int wv  = tid >> 6;
  const int wr  = wv >> 1;              // row half (0/1)
  const int wn  = wv & 1;               // o half (0/1)
  const int l   = tid & 63;
  const int lg  = l >> 4;
  const int ll  = l & 15;

  __shared__ f16 x0s[128 * 56];                       // row stride 112B
  __shared__ f16 xks[(H == 64) ? 128 * 72 : 8];       // row stride 144B
  __shared__ f16 ylds[4 * 64 * 40];                   // per-wave 64x40 (80B rows)

  { // stage x0 tile: 128 rows * 80B
    const uint4* src = (const uint4*)(xt + (size_t)d * (2048 * 40) + (size_t)b0 * 40);
#pragma unroll
    for (int i = 0; i < 3; ++i){
      const int idx = tid + (i << 8);
      if (idx < 640){
        const int r = idx / 5, c = idx - r * 5;
        *(uint4*)((char*)x0s + r * 112 + c * 16) = src[idx];
      }
    }
  }
  if constexpr (H == 64){ // stage x1 tile: 128 rows * 128B
    const uint4* src = (const uint4*)(xkt + (size_t)d * (2048 * 64) + (size_t)b0 * 64);
#pragma unroll
    for (int i = 0; i < 4; ++i){
      const int idx = tid + (i << 8);
      const int r = idx >> 3, c = idx & 7;
      *(uint4*)((char*)xks + r * 144 + c * 16) = src[idx];
    }
  }
  __syncthreads();

  // per-lane A rows: wr*64 + m*16 + ll
  const char* x0row = (const char*)x0s + (wr * 64 + ll) * 112;  // + m*16*112
  const char* xhrow = (H == 64) ? (const char*)xks + (wr * 64 + ll) * 144
                                : x0row;
  constexpr int XH_MSTRIDE = (H == 64) ? 16 * 144 : 16 * 112;

  // lg-rotated slot preload: sl[m][t] = x0 f-block (4t+lg)%5 of row m*16+ll
  f16x8 sl[4][5];
#pragma unroll
  for (int m = 0; m < 4; ++m){
    const char* rb = x0row + m * (16 * 112);
#pragma unroll
    for (int t = 0; t < 5; ++t){
      const int j = (4 * t + lg) % 5;
      sl[m][t] = *(const f16x8*)(rb + j * 16);
    }
  }

  // B fragment pointer: frag(q,n) = bp[q*256 + n*16]
  const f16x8* bp = (const f16x8*)(Wp + (size_t)d * (K * 64) + lg * 512 + (wn * 32 + ll) * 8);

  const f32x4 fz = {0.f, 0.f, 0.f, 0.f};
  f32x4 acc[4][2];
#pragma unroll
  for (int m = 0; m < 4; ++m){ acc[m][0] = fz; acc[m][1] = fz; }

  f16x4 xh4[4], xh4n[4];
#pragma unroll
  for (int m = 0; m < 4; ++m)
    xh4[m] = *(const f16x4*)(xhrow + m * XH_MSTRIDE);

  f16x8 bcur0 = bp[0];
  f16x8 bcur1 = bp[16];

  for (int ks = 0; ks < NSTEP; ++ks){
    const f16x8* bq = bp + (size_t)ks * 1280;
#pragma unroll
    for (int s = 0; s < 5; ++s){
      const f16x8 bn0 = bq[(s + 1) * 256];
      const f16x8 bn1 = bq[(s + 1) * 256 + 16];
      if (s == 2){ // prefetch next ks's xh window (pad-safe at the tail)
#pragma unroll
        for (int m = 0; m < 4; ++m)
          xh4n[m] = *(const f16x4*)(xhrow + m * XH_MSTRIDE + (ks + 1) * 8);
      }
#pragma unroll
      for (int m = 0; m < 4; ++m){
        const int shi = (s < 4) ? s : 3;
        f16 xh;
        if (s == 0) xh = xh4[m][0];
        else        xh = (lg < s) ? xh4[m][s - 1] : xh4[m][shi];
        const f16x8 xs = {xh, xh, xh, xh, xh, xh, xh, xh};
        const f16x8 av = sl[m][s] * xs;
        acc[m][0] = __builtin_amdgcn_mfma_f32_16x16x32_f16(av, bcur0, acc[m][0], 0, 0, 0);
        acc[m][1] = __builtin_amdgcn_mfma_f32_16x16x32_f16(av, bcur1, acc[m][1], 0, 0, 0);
      }
      bcur0 = bn0; bcur1 = bn1;
    }
#pragma unroll
    for (int m = 0; m < 4; ++m) xh4[m] = xh4n[m];
  }

  // epilogue: bias+relu, stage into per-wave LDS tile, coalesced 16B stores
  const float bv0 = bias[wn * 32 + ll];
  const float bv1 = bias[wn * 32 + 16 + ll];
  f16* yw = ylds + wv * (64 * 40);
#pragma unroll
  for (int m = 0; m < 4; ++m)
#pragma unroll
    for (int n = 0; n < 2; ++n)
#pragma unroll
      for (int r = 0; r < 4; ++r){
        const int row = m * 16 + lg * 4 + r;
        const int col = n * 16 + ll;
        float v = acc[m][n][r] + (n ? bv1 : bv0);
        v = v > 0.f ? v : 0.f;
        yw[row * 40 + col] = (f16)v;
      }
  __syncthreads();
  {
    const int row16 = l >> 2, chunk = l & 3;
    f16* ydst = yt + (size_t)d * (2048 * 64);
#pragma unroll
    for (int j = 0; j < 4; ++j){
      const f16x8 vv = *(const f16x8*)((char*)yw + (j * 16 + row16) * 80 + chunk * 16);
      *(f16x8*)(ydst + (size_t)(b0 + wr * 64 + j * 16 + row16) * 64 + wn * 32 + chunk * 8) = vv;
    }
  }
}

// ---------------- final: out[b, :] = sum_d concat(x, x1, x2) ----------------
__global__ __launch_bounds__(192)
void finalize(const float* __restrict__ x, const f16* __restrict__ x1t,
              const f16* __restrict__ y2t, float* __restrict__ out){
  const int b = blockIdx.x;
  const int t = threadIdx.x;
  if (t < 40){
    const float4* p = (const float4*)(x + ((size_t)b * 40 + t) * 32);
    float s = 0.f;
#pragma unroll
    for (int q = 0; q < 8; ++q){
      const float4 v = p[q];
      s += v.x + v.y + v.z + v.w;
    }
    out[(size_t)b * 168 + t] = s;
  } else if (t < 104){
    const int o = t - 40;
    float s = 0.f;
#pragma unroll
    for (int d = 0; d < 32; ++d) s += (float)x1t[(size_t)d * (2048 * 64) + (size_t)b * 64 + o];
    out[(size_t)b * 168 + t] = s;
  } else if (t < 168){
    const int o = t - 104;
    float s = 0.f;
#pragma unroll
    for (int d = 0; d < 32; ++d) s += (float)y2t[(size_t)d * (2048 * 64) + (size_t)b * 64 + o];
    out[(size_t)b * 168 + t] = s;
  }
}

extern "C" void kernel_launch(void* const* d_in, const int* in_sizes, int n_in,
                              void* d_out, int out_size, void* d_ws, size_t ws_size,
                              hipStream_t stream){
  const float* x   = (const float*)d_in[0];
  const float* W0  = (const float*)d_in[1];
  const float* b0v = (const float*)d_in[2];
  const float* W1  = (const float*)d_in[3];
  const float* b1v = (const float*)d_in[4];
  float* out = (float*)d_out;

  char* ws = (char*)d_ws;
  f16* xt  = (f16*)(ws + 0);            // 32*2048*40*2  =  5,242,880
  f16* W0p = (f16*)(ws + 5242880);      // 32*64*1600*2  =  6,553,600
  f16* W1p = (f16*)(ws + 11796480);     // 32*64*2560*2  = 10,485,760
  f16* x1t = (f16*)(ws + 22282240);     // 32*2048*64*2  =  8,388,608
  f16* y2t = (f16*)(ws + 30670848);     // 32*2048*64*2  =  8,388,608
  // total ws use: 39,059,456 bytes

  transpose32<<<2560, 256, 0, stream>>>(x, xt, 81920);
  wprep<<<200, 256, 0, stream>>>(W0, W0p, 1600);
  wprep<<<320, 256, 0, stream>>>(W1, W1p, 2560);

  cin_gemm<40><<<512, 256, 0, stream>>>(xt, nullptr, W0p, b0v, x1t);
  cin_gemm<64><<<512, 256, 0, stream>>>(xt, x1t,     W1p, b1v, y2t);

  finalize<<<2048, 192, 0, stream>>>(x, x1t, y2t, out);
}